// Round 1
// baseline (560.724 us; speedup 1.0000x reference)
//
#include <hip/hip_runtime.h>
#include <stddef.h>

// Problem constants (from reference): x (N=128, C=128, H=56, W=56) fp32,
// w (O=32, K=3, I=128) fp32, out (128, 32, 56, 56) fp32.
#define C_IN  128
#define C_OUT 32
#define HH    56
#define WW    56
#define HW    3136   // 56*56

// Repack w[j,k,i] (strides j:384,k:128,i:1) -> wt[i*96 + j*3 + k] so that for a
// fixed i the 96 weights are contiguous -> merged s_load_dwordx16 in main loop.
__global__ void repack_w_kernel(const float* __restrict__ w, float* __restrict__ wt) {
    int idx = blockIdx.x * 256 + threadIdx.x;
    if (idx < C_IN * C_OUT * 3) {
        int i = idx / (C_OUT * 3);
        int r = idx % (C_OUT * 3);
        int j = r / 3;
        int k = r % 3;
        wt[idx] = w[j * (3 * C_IN) + k * C_IN + i];
    }
}

// One thread = one output pixel (n,h,w), all 32 output channels in registers.
// Wave r of the block handles output row h = blockIdx.x*4 + r; lane = w (56
// active of 64). Weight reads are wave-uniform -> scalar loads on scalar pipe.
template <bool USE_WT>
__global__ __launch_bounds__(256)
void conv_roll_kernel(const float* __restrict__ x, const float* __restrict__ wsrc,
                      float* __restrict__ out) {
    const int n    = blockIdx.y;
    const int wave = threadIdx.x >> 6;
    const int lane = threadIdx.x & 63;
    const int h    = blockIdx.x * 4 + wave;
    const int w    = lane;
    if (w >= WW) return;

    const int hp = (h + HH - 1) % HH;          // x row (output roll along H)
    const int s0 = (w + 54) % WW;              // tap k=0 source col
    const int s1 = (w + 55) % WW;              // tap k=1 source col
    const bool v0 = (w >= 1);                  // tap k=0 validity (W pad)
    const bool v2 = (w <= WW - 2);             // tap k=2 validity (W pad)

    float acc[C_OUT];
#pragma unroll
    for (int j = 0; j < C_OUT; ++j) acc[j] = 0.0f;

    const float* xp = x + (size_t)n * C_IN * HW + (size_t)hp * WW;

#pragma unroll 2
    for (int i = 0; i < C_IN; ++i) {
        const float x0 = v0 ? xp[s0] : 0.0f;
        const float x1 = xp[s1];
        const float x2 = v2 ? xp[w] : 0.0f;
        if (USE_WT) {
            const float* wp = wsrc + i * (C_OUT * 3);
#pragma unroll
            for (int j = 0; j < C_OUT; ++j) {
                acc[j] = fmaf(x2, wp[j * 3 + 2],
                         fmaf(x1, wp[j * 3 + 1],
                         fmaf(x0, wp[j * 3 + 0], acc[j])));
            }
        } else {
            const float* wp = wsrc + i;
#pragma unroll
            for (int j = 0; j < C_OUT; ++j) {
                acc[j] = fmaf(x2, wp[j * 384 + 256],
                         fmaf(x1, wp[j * 384 + 128],
                         fmaf(x0, wp[j * 384 + 0], acc[j])));
            }
        }
        xp += HW;
    }

    float* op = out + (size_t)n * C_OUT * HW + (size_t)h * WW + w;
#pragma unroll
    for (int j = 0; j < C_OUT; ++j) op[(size_t)j * HW] = acc[j];
}

extern "C" void kernel_launch(void* const* d_in, const int* in_sizes, int n_in,
                              void* d_out, int out_size, void* d_ws, size_t ws_size,
                              hipStream_t stream) {
    const float* x = (const float*)d_in[0];
    const float* w = (const float*)d_in[1];
    float* out = (float*)d_out;

    dim3 grid(HH / 4, 128);  // (h-groups of 4 rows, n)
    dim3 block(256);

    const size_t wt_bytes = (size_t)C_IN * C_OUT * 3 * sizeof(float);  // 48 KiB
    if (ws_size >= wt_bytes) {
        float* wt = (float*)d_ws;
        repack_w_kernel<<<(C_IN * C_OUT * 3 + 255) / 256, 256, 0, stream>>>(w, wt);
        conv_roll_kernel<true><<<grid, block, 0, stream>>>(x, wt, out);
    } else {
        conv_roll_kernel<false><<<grid, block, 0, stream>>>(x, w, out);
    }
}

// Round 2
// 325.452 us; speedup vs baseline: 1.7229x; 1.7229x over previous
//
#include <hip/hip_runtime.h>
#include <stddef.h>

// out[n,j,h,w] = sum_{k,i} x[n,i,(h+55)%56, srccol(k,w)] * w[j,k,i]
//   tap k=0: valid w>=1, col (w+54)%56
//   tap k=1: always,    col (w+55)%56
//   tap k=2: valid w<=54, col w
// GEMM view: M=32 (j), K=384 (tap*128+i), N=spatial. bf16 MFMA 16x16x32.

#define C_IN   128
#define C_OUT  32
#define HH     56
#define WW     56
#define HW     3136
#define KTOT   384
#define WSTRIDE 392          // padded K-stride for weights (bf16 elems), 784B = 49*16B (odd chunks)
#define XSTRIDE 136          // padded ch-stride for XT (bf16 elems), 272B = 17*16B (odd chunks)

typedef short bf16x8 __attribute__((ext_vector_type(8)));
typedef float f32x4  __attribute__((ext_vector_type(4)));

static __device__ __forceinline__ unsigned short f2b(float f) {
    unsigned u = __builtin_bit_cast(unsigned, f);
    unsigned r = u + 0x7FFFu + ((u >> 16) & 1u);   // RNE
    return (unsigned short)(r >> 16);
}

// Pack w[j,k,i] fp32 -> ws[j][tap*128+i] bf16 with padded stride (source K-order
// k*128+i already matches; just cast + pad).
__global__ void pack_w_kernel(const float* __restrict__ w, unsigned short* __restrict__ ws) {
    int idx = blockIdx.x * 256 + threadIdx.x;
    if (idx < C_OUT * WSTRIDE) {
        int j = idx / WSTRIDE;
        int r = idx % WSTRIDE;
        float v = (r < KTOT) ? w[j * KTOT + r] : 0.0f;
        ws[idx] = f2b(v);
    }
}

__global__ __launch_bounds__(256, 6)
void conv_mfma_kernel(const float* __restrict__ x, const unsigned short* __restrict__ ws,
                      float* __restrict__ out) {
    // block = one (n, h) output row
    const int bid = blockIdx.x;
    const int n = bid / HH;
    const int h = bid % HH;
    const int hp = (h + HH - 1) % HH;   // source x row

    const int tid  = threadIdx.x;
    const int lane = tid & 63;
    const int grp  = tid >> 6;          // wave id 0..3

    // XT[col][ch] bf16, col 0..55 real, col 56 = zeros. stride 136 elems (272B).
    __shared__ __align__(16) unsigned short XT[57 * XSTRIDE];

    // ---- stage x row: thread (grp, lane=col) loads ch = grp*32 .. +31 ----
    {
        const int c = lane;
        const int i0 = grp * 32;
        if (c < WW) {
            const float* xp = x + (size_t)n * (C_IN * HW) + (size_t)i0 * HW + hp * WW + c;
            float v[32];
#pragma unroll
            for (int s = 0; s < 32; ++s) v[s] = xp[(size_t)s * HW];
            unsigned pk[16];
#pragma unroll
            for (int s = 0; s < 16; ++s)
                pk[s] = (unsigned)f2b(v[2 * s]) | ((unsigned)f2b(v[2 * s + 1]) << 16);
            uint4* dst = (uint4*)&XT[c * XSTRIDE + i0];
#pragma unroll
            for (int q = 0; q < 4; ++q)
                dst[q] = make_uint4(pk[4 * q], pk[4 * q + 1], pk[4 * q + 2], pk[4 * q + 3]);
        } else if (c == WW) {
            // zero column for invalid taps / N-tile padding
            uint4* dst = (uint4*)&XT[WW * XSTRIDE + i0];
#pragma unroll
            for (int q = 0; q < 4; ++q) dst[q] = make_uint4(0, 0, 0, 0);
        }
    }
    __syncthreads();

    // ---- MFMA: wave grp owns N-tile n0 = 16*grp (spatial cols) ----
    const int n0 = grp * 16;
    const int nn = n0 + (lane & 15);            // output w this lane covers (may be >=56 pad)
    const int kb = (lane >> 4) * 8;             // k sub-offset within 32-chunk

    int cc0 = (nn >= 1 && nn <= 55) ? (nn + 54) % WW : WW;
    int cc1 = (nn <= 55) ? (nn + 55) % WW : WW;
    int cc2 = (nn <= 54) ? nn : WW;
    const unsigned short* bp0 = &XT[cc0 * XSTRIDE + kb];
    const unsigned short* bp1 = &XT[cc1 * XSTRIDE + kb];
    const unsigned short* bp2 = &XT[cc2 * XSTRIDE + kb];

    const unsigned short* wp = ws + (lane & 15) * WSTRIDE + kb;

    f32x4 acc0 = {0.f, 0.f, 0.f, 0.f};
    f32x4 acc1 = {0.f, 0.f, 0.f, 0.f};

#pragma unroll
    for (int c = 0; c < 12; ++c) {
        const int tap = c >> 2;                 // compile-time per unrolled iter
        const int ib = (c & 3) * 32;
        const unsigned short* bp = (tap == 0) ? bp0 : (tap == 1) ? bp1 : bp2;
        bf16x8 b  = *(const bf16x8*)(bp + ib);
        bf16x8 a0 = *(const bf16x8*)(wp + c * 32);
        bf16x8 a1 = *(const bf16x8*)(wp + 16 * WSTRIDE + c * 32);
        acc0 = __builtin_amdgcn_mfma_f32_16x16x32_bf16(a0, b, acc0, 0, 0, 0);
        acc1 = __builtin_amdgcn_mfma_f32_16x16x32_bf16(a1, b, acc1, 0, 0, 0);
    }

    // ---- epilogue: C/D layout col=lane&15 (n), row=(lane>>4)*4+reg (m=j) ----
    if (nn < WW) {
        float* ob = out + (size_t)n * (C_OUT * HW) + (size_t)h * WW + nn;
        const int j0 = (lane >> 4) * 4;
#pragma unroll
        for (int r = 0; r < 4; ++r) {
            ob[(size_t)(j0 + r) * HW]      = acc0[r];
            ob[(size_t)(j0 + r + 16) * HW] = acc1[r];
        }
    }
}

extern "C" void kernel_launch(void* const* d_in, const int* in_sizes, int n_in,
                              void* d_out, int out_size, void* d_ws, size_t ws_size,
                              hipStream_t stream) {
    const float* x = (const float*)d_in[0];
    const float* w = (const float*)d_in[1];
    float* out = (float*)d_out;
    unsigned short* ws = (unsigned short*)d_ws;   // 32*392*2 = 25088 B needed

    pack_w_kernel<<<(C_OUT * WSTRIDE + 255) / 256, 256, 0, stream>>>(w, ws);
    conv_mfma_kernel<<<dim3(128 * HH), dim3(256), 0, stream>>>(x, ws, out);
}

// Round 3
// 322.541 us; speedup vs baseline: 1.7385x; 1.0090x over previous
//
#include <hip/hip_runtime.h>
#include <stddef.h>

// out[n,j,h,w] = sum_{k,i} x[n,i,(h+55)%56, srccol(k,w)] * w[j,k,i]
//   tap k=0: valid w>=1,  col (w+54)%56
//   tap k=1: always,      col (w+55)%56
//   tap k=2: valid w<=54, col w
// GEMM view: M=32 (j), K=384 (tap*128+i), N=spatial. bf16 MFMA 16x16x32.
// Block = (n, 2 output rows). Staging: float4 loads lanes-along-ch (1KiB/inst,
// L1 merges the 4 c4-adjacent insts per 64B line), b16 LDS scatter is
// conflict-free (bank = const + ch/2 -> 2 lanes/bank).

#define C_IN   128
#define C_OUT  32
#define HH     56
#define WW     56
#define HW     3136
#define KTOT   384
#define WSTRIDE 392              // padded K-stride for weights (bf16 elems)
#define XSTRIDE 136              // ushorts per col (272B = 17x16B, odd 16B chunks)
#define XROW   (57 * XSTRIDE)    // one row-buffer: 56 real cols + zero col

typedef short bf16x8 __attribute__((ext_vector_type(8)));
typedef float f32x4  __attribute__((ext_vector_type(4)));

static __device__ __forceinline__ unsigned short f2b(float f) {
    unsigned u = __builtin_bit_cast(unsigned, f);
    unsigned r = u + 0x7FFFu + ((u >> 16) & 1u);   // RNE
    return (unsigned short)(r >> 16);
}

__global__ void pack_w_kernel(const float* __restrict__ w, unsigned short* __restrict__ ws) {
    int idx = blockIdx.x * 256 + threadIdx.x;
    if (idx < C_OUT * WSTRIDE) {
        int j = idx / WSTRIDE;
        int r = idx % WSTRIDE;
        ws[idx] = f2b(r < KTOT ? w[j * KTOT + r] : 0.0f);
    }
}

__global__ __launch_bounds__(256, 5)
void conv_mfma_kernel(const float* __restrict__ x, const unsigned short* __restrict__ ws,
                      float* __restrict__ out) {
    const int bid  = blockIdx.x;
    const int n    = bid / (HH / 2);
    const int h0   = (bid % (HH / 2)) * 2;
    const int tid  = threadIdx.x;
    const int lane = tid & 63;
    const int grp  = tid >> 6;

    // XT[row r][col][ch] bf16; col 56 = zeros (invalid taps / N-tile pad)
    __shared__ __align__(16) unsigned short XT[2 * XROW];

    if (tid < 32) {
        int r = tid >> 4, seg = tid & 15;
        *(uint4*)&XT[r * XROW + WW * XSTRIDE + seg * 8] = make_uint4(0, 0, 0, 0);
    }

    const int hp0 = (h0 + HH - 1) % HH;   // source row for output h0
    // source row for output h0+1 is h0 itself
    const float* xb = x + (size_t)n * (C_IN * HW);

    // ---- stage 2 source rows: 2*128ch*14 float4 = 3584 tasks = 14*256 ----
#pragma unroll
    for (int p = 0; p < 14; ++p) {
        const int task = p * 256 + tid;
        const int ch   = task & 127;
        const int rest = task >> 7;           // 0..27
        const int c4   = rest % 14;           // float4 index along row
        const int r    = rest / 14;           // 0/1, wave-uniform
        const int hrow = (r == 0) ? hp0 : h0;
        const float4 v = *(const float4*)(xb + (size_t)ch * HW + hrow * WW + c4 * 4);
        unsigned short* dst = &XT[r * XROW + (c4 * 4) * XSTRIDE + ch];
        dst[0]           = f2b(v.x);
        dst[XSTRIDE]     = f2b(v.y);
        dst[2 * XSTRIDE] = f2b(v.z);
        dst[3 * XSTRIDE] = f2b(v.w);
    }
    __syncthreads();

    // ---- MFMA: wave grp owns cols n0=grp*16..+15 for BOTH rows ----
    const int nn = grp * 16 + (lane & 15);
    const int kb = (lane >> 4) * 8;
    const int cc0 = (nn >= 1 && nn <= 55) ? (nn + 54) % WW : WW;
    const int cc1 = (nn <= 55) ? (nn + 55) % WW : WW;
    const int cc2 = (nn <= 54) ? nn : WW;
    const unsigned short* b00 = &XT[cc0 * XSTRIDE + kb];
    const unsigned short* b01 = &XT[cc1 * XSTRIDE + kb];
    const unsigned short* b02 = &XT[cc2 * XSTRIDE + kb];

    const unsigned short* wp = ws + (lane & 15) * WSTRIDE + kb;

    f32x4 acc00 = {0.f,0.f,0.f,0.f}, acc01 = {0.f,0.f,0.f,0.f};
    f32x4 acc10 = {0.f,0.f,0.f,0.f}, acc11 = {0.f,0.f,0.f,0.f};

#pragma unroll
    for (int c = 0; c < 12; ++c) {
        const int tap = c >> 2;
        const int ib  = (c & 3) * 32;
        const unsigned short* bp = (tap == 0) ? b00 : (tap == 1) ? b01 : b02;
        bf16x8 A0 = *(const bf16x8*)(wp + c * 32);
        bf16x8 A1 = *(const bf16x8*)(wp + 16 * WSTRIDE + c * 32);
        bf16x8 B0 = *(const bf16x8*)(bp + ib);            // row 0
        bf16x8 B1 = *(const bf16x8*)(bp + XROW + ib);     // row 1
        acc00 = __builtin_amdgcn_mfma_f32_16x16x32_bf16(A0, B0, acc00, 0, 0, 0);
        acc01 = __builtin_amdgcn_mfma_f32_16x16x32_bf16(A1, B0, acc01, 0, 0, 0);
        acc10 = __builtin_amdgcn_mfma_f32_16x16x32_bf16(A0, B1, acc10, 0, 0, 0);
        acc11 = __builtin_amdgcn_mfma_f32_16x16x32_bf16(A1, B1, acc11, 0, 0, 0);
    }

    // ---- epilogue: C/D layout col=lane&15 (w), row=(lane>>4)*4+reg (j) ----
    if (nn < WW) {
        const int j0 = (lane >> 4) * 4;
        float* ob = out + (size_t)n * (C_OUT * HW) + (size_t)h0 * WW + nn;
#pragma unroll
        for (int r = 0; r < 4; ++r) {
            ob[(size_t)(j0 + r) * HW]           = acc00[r];
            ob[(size_t)(j0 + r + 16) * HW]      = acc01[r];
            ob[(size_t)(j0 + r) * HW + WW]      = acc10[r];
            ob[(size_t)(j0 + r + 16) * HW + WW] = acc11[r];
        }
    }
}

extern "C" void kernel_launch(void* const* d_in, const int* in_sizes, int n_in,
                              void* d_out, int out_size, void* d_ws, size_t ws_size,
                              hipStream_t stream) {
    const float* x = (const float*)d_in[0];
    const float* w = (const float*)d_in[1];
    float* out = (float*)d_out;
    unsigned short* ws = (unsigned short*)d_ws;   // 32*392*2 = 25088 B needed

    pack_w_kernel<<<(C_OUT * WSTRIDE + 255) / 256, 256, 0, stream>>>(w, ws);
    conv_mfma_kernel<<<dim3(128 * (HH / 2)), dim3(256), 0, stream>>>(x, ws, out);
}

// Round 4
// 303.483 us; speedup vs baseline: 1.8476x; 1.0628x over previous
//
#include <hip/hip_runtime.h>
#include <stddef.h>

// out[n,j,h,w] = sum_{k,i} x[n,i,(h+55)%56, srccol(k,w)] * w[j,k,i]
//   tap k=0: valid w>=1,  col (w+54)%56
//   tap k=1: always,      col (w+55)%56
//   tap k=2: valid w<=54, col w
// GEMM view: M=32 (j), K=384 (tap*128+i), N=spatial. bf16 MFMA 16x16x32.
// Block = (n, 4 output rows h0..h0+3) -> reads source rows h0-1..h0+2, which
// are CONTIGUOUS in x per channel: 896B HBM granules (vs 448B before) to fix
// scattered-read delivery. Staging: 56 lanes sweep one granule per wave-inst.

#define C_IN   128
#define C_OUT  32
#define HH     56
#define WW     56
#define HW     3136
#define KTOT   384
#define WSTRIDE 392              // padded K-stride for weights (bf16 elems)
#define XSTRIDE 136              // ushorts per col (272B = 17x16B -> bank-balanced b128)
#define XROWSZ (57 * XSTRIDE)    // one source row: 56 real cols + zero col 56

typedef short bf16x8 __attribute__((ext_vector_type(8)));
typedef float f32x4  __attribute__((ext_vector_type(4)));

static __device__ __forceinline__ unsigned short f2b(float f) {
    unsigned u = __builtin_bit_cast(unsigned, f);
    unsigned r = u + 0x7FFFu + ((u >> 16) & 1u);   // RNE
    return (unsigned short)(r >> 16);
}

__global__ void pack_w_kernel(const float* __restrict__ w, unsigned short* __restrict__ ws) {
    int idx = blockIdx.x * 256 + threadIdx.x;
    if (idx < C_OUT * WSTRIDE) {
        int j = idx / WSTRIDE;
        int r = idx % WSTRIDE;
        ws[idx] = f2b(r < KTOT ? w[j * KTOT + r] : 0.0f);
    }
}

__global__ __launch_bounds__(256, 2)
void conv_mfma_kernel(const float* __restrict__ x, const unsigned short* __restrict__ ws,
                      float* __restrict__ out) {
    const int bid  = blockIdx.x;
    const int n    = bid / (HH / 4);
    const int h0   = (bid % (HH / 4)) * 4;
    const int tid  = threadIdx.x;
    const int lane = tid & 63;
    const int grp  = tid >> 6;

    // XT[src row r (0..3)][col 0..56][ch] bf16; col 56 = zeros
    __shared__ __align__(16) unsigned short XT[4 * XROWSZ];   // 62016 B

    // zero col 56 of all 4 rows: 4*136 ushorts = 1088 B = 68 uint4
    if (tid < 68) {
        int r = tid / 17, off = (tid % 17) * 8;
        *(uint4*)&XT[r * XROWSZ + WW * XSTRIDE + off] = make_uint4(0, 0, 0, 0);
    }

    const float* xb = x + (size_t)n * (C_IN * HW);

    // ---- stage 4 source rows. wave-inst = one 896B contiguous granule ----
    // lane<56: q=lane -> (r=q/14, c4=q%14); ch = p*4 + wave. 32 iters.
    {
        const int q  = lane;
        const int r  = q / 14;
        const int c4 = q % 14;
        const int hs = (h0 + 55 + r) % HH;          // source row for LDS row r
        const size_t rowoff = (size_t)hs * WW + c4 * 4;
        unsigned short* dst0 = &XT[r * XROWSZ + (c4 * 4) * XSTRIDE];
#pragma unroll 8
        for (int p = 0; p < 32; ++p) {
            const int ch = p * 4 + grp;
            if (q < WW) {
                const float4 v = *(const float4*)(xb + (size_t)ch * HW + rowoff);
                unsigned short* dst = dst0 + ch;
                dst[0]           = f2b(v.x);
                dst[XSTRIDE]     = f2b(v.y);
                dst[2 * XSTRIDE] = f2b(v.z);
                dst[3 * XSTRIDE] = f2b(v.w);
            }
        }
    }
    __syncthreads();

    // ---- MFMA: wave g computes output row h0+g from LDS row g ----
    const int l15 = lane & 15;
    const int kb  = (lane >> 4) * 8;
    const unsigned short* Xr = &XT[grp * XROWSZ];

    const unsigned short* bp[4][3];
#pragma unroll
    for (int ct = 0; ct < 4; ++ct) {
        const int nn = ct * 16 + l15;
        const int cc0 = (nn >= 1 && nn <= 55) ? (nn + 54) % WW : WW;
        const int cc1 = (nn <= 55) ? (nn + 55) % WW : WW;
        const int cc2 = (nn <= 54) ? nn : WW;
        bp[ct][0] = Xr + cc0 * XSTRIDE + kb;
        bp[ct][1] = Xr + cc1 * XSTRIDE + kb;
        bp[ct][2] = Xr + cc2 * XSTRIDE + kb;
    }

    const unsigned short* wp = ws + l15 * WSTRIDE + kb;

    f32x4 acc[4][2];
#pragma unroll
    for (int ct = 0; ct < 4; ++ct) {
        acc[ct][0] = (f32x4){0.f, 0.f, 0.f, 0.f};
        acc[ct][1] = (f32x4){0.f, 0.f, 0.f, 0.f};
    }

#pragma unroll
    for (int c = 0; c < 12; ++c) {
        const int tap = c >> 2;
        const int ib  = (c & 3) * 32;
        bf16x8 A0 = *(const bf16x8*)(wp + c * 32);
        bf16x8 A1 = *(const bf16x8*)(wp + 16 * WSTRIDE + c * 32);
#pragma unroll
        for (int ct = 0; ct < 4; ++ct) {
            bf16x8 B = *(const bf16x8*)(bp[ct][tap] + ib);
            acc[ct][0] = __builtin_amdgcn_mfma_f32_16x16x32_bf16(A0, B, acc[ct][0], 0, 0, 0);
            acc[ct][1] = __builtin_amdgcn_mfma_f32_16x16x32_bf16(A1, B, acc[ct][1], 0, 0, 0);
        }
    }

    // ---- epilogue: C/D layout col=lane&15 (w), row=(lane>>4)*4+reg (j) ----
    {
        const int h  = h0 + grp;
        const int j0 = (lane >> 4) * 4;
        float* ob = out + (size_t)n * (C_OUT * HW) + (size_t)h * WW;
#pragma unroll
        for (int ct = 0; ct < 4; ++ct) {
            const int nn = ct * 16 + l15;
            if (nn < WW) {
#pragma unroll
                for (int r = 0; r < 4; ++r) {
                    ob[(size_t)(j0 + r) * HW + nn]      = acc[ct][0][r];
                    ob[(size_t)(j0 + r + 16) * HW + nn] = acc[ct][1][r];
                }
            }
        }
    }
}

extern "C" void kernel_launch(void* const* d_in, const int* in_sizes, int n_in,
                              void* d_out, int out_size, void* d_ws, size_t ws_size,
                              hipStream_t stream) {
    const float* x = (const float*)d_in[0];
    const float* w = (const float*)d_in[1];
    float* out = (float*)d_out;
    unsigned short* ws = (unsigned short*)d_ws;   // 32*392*2 = 25088 B needed

    pack_w_kernel<<<(C_OUT * WSTRIDE + 255) / 256, 256, 0, stream>>>(w, ws);
    conv_mfma_kernel<<<dim3(128 * (HH / 4)), dim3(256), 0, stream>>>(x, ws, out);
}